// Round 18
// baseline (166.724 us; speedup 1.0000x reference)
//
#include <hip/hip_runtime.h>

typedef float f32x4 __attribute__((ext_vector_type(4)));
typedef float f32x16 __attribute__((ext_vector_type(16)));
typedef short s16x8 __attribute__((ext_vector_type(8)));
typedef unsigned int u32x4 __attribute__((ext_vector_type(4)));

#define B_SZ 4
#define T_SZ 2048
#define D_SZ 1024
#define NH 16
#define HD 64
#define KVB 256

// scale folded into Q: hd^-0.5 * log2(e)
#define CLQ (0.125f * 1.44269504089f)

// ---------- helpers ----------
__device__ __forceinline__ unsigned short f2b(float f) {
  unsigned int u = __builtin_bit_cast(unsigned int, f);
  unsigned int r = (u + 0x7fffu + ((u >> 16) & 1u)) >> 16;  // RNE
  return (unsigned short)r;
}

__device__ __forceinline__ void gld_lds16(void* lds, const void* g) {
  __builtin_amdgcn_global_load_lds(
      (const __attribute__((address_space(1))) unsigned int*)g,
      (__attribute__((address_space(3))) unsigned int*)lds, 16, 0, 0);
}

__device__ __forceinline__ float vsum16(f32x16 v) {
  float t0 = (v[0] + v[1]) + (v[2] + v[3]);
  float t1 = (v[4] + v[5]) + (v[6] + v[7]);
  float t2 = (v[8] + v[9]) + (v[10] + v[11]);
  float t3 = (v[12] + v[13]) + (v[14] + v[15]);
  return (t0 + t1) + (t2 + t3);
}

// ---------- fp32 -> bf16 cast: x + all 4 weights in ONE dispatch ----------
__global__ void cast_all(const float* __restrict__ x,
                         const float* __restrict__ w0, const float* __restrict__ w1,
                         const float* __restrict__ w2, const float* __restrict__ w3,
                         unsigned short* __restrict__ xo,
                         unsigned short* __restrict__ o0, unsigned short* __restrict__ o1,
                         unsigned short* __restrict__ o2, unsigned short* __restrict__ o3) {
  int i = blockIdx.x * blockDim.x + threadIdx.x;
  const float* src;
  unsigned short* dst;
  int j;
  if (i < 2097152) {                 // x
    src = x; dst = xo; j = i;
  } else {
    const int t = i - 2097152;
    const int w = t >> 18;           // 262144 float4 per weight matrix
    j = t & 262143;
    src = (w == 0) ? w0 : (w == 1) ? w1 : (w == 2) ? w2 : w3;
    dst = (w == 0) ? o0 : (w == 1) ? o1 : (w == 2) ? o2 : o3;
  }
  float4 v = reinterpret_cast<const float4*>(src)[j];
  ushort4 o;
  o.x = f2b(v.x); o.y = f2b(v.y); o.z = f2b(v.z); o.w = f2b(v.w);
  reinterpret_cast<ushort4*>(dst)[j] = o;
}

// ---------- GEMM core (128x128 tile, BK=128, both-sides swizzle) ----------
// R18: BK=128 (8 staging rounds, was 16), LDS rows 256B; XOR swizzle confined
// to 128B halves on both write (slot^=(row&7)) and read (byte^=((row&7)<<4))
// sides — same algebra as R17's verified V staging. MFMA in a single-body
// kk sub-loop (unroll 1, R15-proven). XCD-bijective block swizzle keeps each
// XCD's x-row-panel (2MB) L2-resident.
#define BM 128
#define BN 128
#define BKG 128

// Fused QKV projection: one dispatch, grid (64, 24).
__global__ __launch_bounds__(256, 2) void gemm_qkv(
    const unsigned short* __restrict__ A,
    const unsigned short* __restrict__ Wq,
    const unsigned short* __restrict__ Wk,
    const unsigned short* __restrict__ Wv,
    unsigned short* __restrict__ Qo,
    unsigned short* __restrict__ Ko,
    unsigned short* __restrict__ Vto) {
  __shared__ __align__(16) char As[BM * 256];   // 128 rows x 256B, swizzled
  __shared__ __align__(16) char Ws[BN * 256];
  const int tid = threadIdx.x, wid = tid >> 6, lane = tid & 63;

  // XCD-bijective swizzle: 1536 blocks = 8 XCD x 192; each XCD owns 8
  // row-blocks (x-panel resident in its L2) x all 24 col/sel slices.
  const int lin = blockIdx.y * gridDim.x + blockIdx.x;
  const int xcd = lin & 7, t = lin >> 3;        // t 0..191
  const int wx = xcd * 8 + (t & 7);             // row-block 0..63
  const int wy = t >> 3;                        // col/sel 0..23
  const int sel = wy >> 3;                      // 0=Q 1=K 2=V
  const unsigned short* W = (sel == 0) ? Wq : (sel == 1) ? Wk : Wv;
  const int row0 = wx * BM, col0 = (wy & 7) * BN;

  const int wr = (wid >> 1) * 64, wc = (wid & 1) * 64;
  const int fr = lane & 15;
  const int kgB = (lane >> 4) * 16;             // byte offset of 16B k-chunk
  f32x4 acc[4][4] = {};

  // staging: 32 chunks/matrix of 1024B = 4 rows x 256B; 8 insts/thread/matrix
  const int srow = lane >> 4;                   // row within 4-row chunk
  const int s16 = lane & 15;                    // 16B slot within 256B row

  for (int k0 = 0; k0 < D_SZ; k0 += BKG) {
    __syncthreads();
#pragma unroll
    for (int i = 0; i < 8; ++i) {
      const int c = wid + 4 * i;
      const int row = c * 4 + srow;
      const int ss = s16 ^ (row & 7);           // pre-swizzled source slot
      gld_lds16(As + c * 1024, &A[(row0 + row) * D_SZ + k0 + ss * 8]);
      gld_lds16(Ws + c * 1024, &W[(col0 + row) * D_SZ + k0 + ss * 8]);
    }
    __syncthreads();
#pragma unroll 1
    for (int kks = 0; kks < 4; ++kks) {         // 4 x K=32 sub-steps
      s16x8 af[4], bf[4];
#pragma unroll
      for (int m = 0; m < 4; ++m) {
        const int row = wr + m * 16 + fr;
        af[m] = *(const s16x8*)(As + row * 256 + ((kks * 64 + kgB) ^ ((row & 7) << 4)));
      }
#pragma unroll
      for (int n = 0; n < 4; ++n) {
        const int row = wc + n * 16 + fr;
        bf[n] = *(const s16x8*)(Ws + row * 256 + ((kks * 64 + kgB) ^ ((row & 7) << 4)));
      }
#pragma unroll
      for (int m = 0; m < 4; ++m)
#pragma unroll
        for (int n = 0; n < 4; ++n)
          acc[m][n] = __builtin_amdgcn_mfma_f32_16x16x32_bf16(af[m], bf[n], acc[m][n], 0, 0, 0);
    }
  }

  const int crow = row0 + wr + ((lane >> 4) << 2);
  const int ccol = col0 + wc + fr;
  if (sel == 2) {  // Vt: transposed per (b,h)
#pragma unroll
    for (int m = 0; m < 4; ++m)
#pragma unroll
      for (int n = 0; n < 4; ++n) {
        ushort4 pk;
        pk.x = f2b(acc[m][n][0]); pk.y = f2b(acc[m][n][1]);
        pk.z = f2b(acc[m][n][2]); pk.w = f2b(acc[m][n][3]);
        const int tok = crow + m * 16;
        const int c = ccol + n * 16;
        *(ushort4*)&Vto[((tok >> 11) * 1024 + c) * 2048 + (tok & 2047)] = pk;
      }
  } else {
    unsigned short* C = (sel == 0) ? Qo : Ko;
    const float s = (sel == 0) ? CLQ : 1.0f;
#pragma unroll
    for (int m = 0; m < 4; ++m)
#pragma unroll
      for (int n = 0; n < 4; ++n)
#pragma unroll
        for (int r = 0; r < 4; ++r)
          C[(crow + m * 16 + r) * D_SZ + ccol + n * 16] = f2b(acc[m][n][r] * s);
  }
}

// O-projection: C[M,N] f32 = A[M,K] * W[N,K]^T  (same BK=128 core)
__global__ __launch_bounds__(256, 2) void gemm_out(
    const unsigned short* __restrict__ A,
    const unsigned short* __restrict__ W,
    float* __restrict__ C, int M, int N, int K) {
  __shared__ __align__(16) char As[BM * 256];
  __shared__ __align__(16) char Ws[BN * 256];
  const int tid = threadIdx.x, wid = tid >> 6, lane = tid & 63;

  // XCD-bijective swizzle: 512 blocks = 8 XCD x 64 (8 row-blocks x 8 cols)
  const int lin = blockIdx.y * gridDim.x + blockIdx.x;
  const int xcd = lin & 7, t = lin >> 3;        // t 0..63
  const int wx = xcd * 8 + (t & 7);             // row-block 0..63
  const int wy = t >> 3;                        // col-block 0..7
  const int row0 = wx * BM, col0 = wy * BN;

  const int wr = (wid >> 1) * 64, wc = (wid & 1) * 64;
  const int fr = lane & 15;
  const int kgB = (lane >> 4) * 16;
  f32x4 acc[4][4] = {};

  const int srow = lane >> 4;
  const int s16 = lane & 15;

  for (int k0 = 0; k0 < K; k0 += BKG) {
    __syncthreads();
#pragma unroll
    for (int i = 0; i < 8; ++i) {
      const int c = wid + 4 * i;
      const int row = c * 4 + srow;
      const int ss = s16 ^ (row & 7);
      gld_lds16(As + c * 1024, &A[(row0 + row) * K + k0 + ss * 8]);
      gld_lds16(Ws + c * 1024, &W[(col0 + row) * K + k0 + ss * 8]);
    }
    __syncthreads();
#pragma unroll 1
    for (int kks = 0; kks < 4; ++kks) {
      s16x8 af[4], bf[4];
#pragma unroll
      for (int m = 0; m < 4; ++m) {
        const int row = wr + m * 16 + fr;
        af[m] = *(const s16x8*)(As + row * 256 + ((kks * 64 + kgB) ^ ((row & 7) << 4)));
      }
#pragma unroll
      for (int n = 0; n < 4; ++n) {
        const int row = wc + n * 16 + fr;
        bf[n] = *(const s16x8*)(Ws + row * 256 + ((kks * 64 + kgB) ^ ((row & 7) << 4)));
      }
#pragma unroll
      for (int m = 0; m < 4; ++m)
#pragma unroll
        for (int n = 0; n < 4; ++n)
          acc[m][n] = __builtin_amdgcn_mfma_f32_16x16x32_bf16(af[m], bf[n], acc[m][n], 0, 0, 0);
    }
  }

  const int crow = row0 + wr + ((lane >> 4) << 2);
  const int ccol = col0 + wc + fr;
#pragma unroll
  for (int m = 0; m < 4; ++m)
#pragma unroll
    for (int n = 0; n < 4; ++n)
#pragma unroll
      for (int r = 0; r < 4; ++r)
        C[(crow + m * 16 + r) * N + ccol + n * 16] = acc[m][n][r];
}

// ---------- flash attention: KVB=256, single-body sub loop (R17-verified) ----
__global__ __launch_bounds__(256, 2) void attn_kernel(
    const unsigned short* __restrict__ Q,
    const unsigned short* __restrict__ K,
    const unsigned short* __restrict__ Vt,
    unsigned short* __restrict__ O) {
  __shared__ __align__(16) char Kl[KVB * 128];   // [kv 0..255][128B], swizzled
  __shared__ __align__(16) char Vl[HD * 512];    // [d 0..63][512B], swizzled per 128B group

  const int tid = threadIdx.x, wid = tid >> 6, lane = tid & 63;
  const int ql = lane & 31;
  const int hi = lane >> 5;
  const int srow = lane >> 3;    // K staging: row within 8-row chunk
  const int sc = lane & 7;       // K staging: 16B chunk within 128B row
  const int vrow = lane >> 5;    // V staging: row within 2-row chunk (512B rows)
  const int vsc = lane & 31;     // V staging: 16B slot within 512B row

  // bijective XCD swizzle: 512 blocks = 8 XCD * 64
  const int lin = blockIdx.y * gridDim.x + blockIdx.x;
  const int work = (lin & 7) * 64 + (lin >> 3);
  const int qc = work & 7, bh = work >> 3;
  const int b = bh >> 4, h = bh & 15;
  const int q0 = qc * 256 + wid * 64;
  const int qkbase = b * T_SZ * D_SZ + h * HD;
  const int vtbase = (b * D_SZ + h * HD) * T_SZ;

  // Q B-fragments for both chunks (already scaled by CLQ)
  s16x8 qf[2][4];
#pragma unroll
  for (int c = 0; c < 2; ++c)
#pragma unroll
    for (int kq = 0; kq < 4; ++kq)
      qf[c][kq] = *(const s16x8*)&Q[qkbase + (q0 + c * 32 + ql) * D_SZ + kq * 16 + hi * 8];

  f32x16 ot[2][2] = {};             // [chunk][dblk]
  float l[2] = {0.f, 0.f};          // per-half partial sums

#pragma unroll 1
  for (int kv0 = 0; kv0 < T_SZ; kv0 += KVB) {
    __syncthreads();  // previous round's LDS reads complete
#pragma unroll
    for (int i = 0; i < 8; ++i) {
      const int c = wid + 4 * i;
      const int row = c * 8 + srow;
      const int sch = sc ^ (row & 7);
      gld_lds16(Kl + c * 1024, &K[qkbase + (kv0 + row) * D_SZ + sch * 8]);
    }
#pragma unroll
    for (int i = 0; i < 8; ++i) {
      const int c = wid + 4 * i;
      const int row = c * 2 + vrow;
      const int sslot = vsc ^ (row & 7);
      gld_lds16(Vl + c * 1024, &Vt[vtbase + row * T_SZ + kv0 + sslot * 8]);
    }
    __syncthreads();  // staging visible (syncthreads drains vmcnt)

#pragma unroll 1
    for (int sub = 0; sub < 4; ++sub) {
      // V fragments (8 ds_read_b128), slots in sub's 128B group
      s16x8 vfr[4][2];
#pragma unroll
      for (int ks = 0; ks < 4; ++ks)
#pragma unroll
        for (int dblk = 0; dblk < 2; ++dblk) {
          const int vr = dblk * 32 + ql;
          vfr[ks][dblk] = *(const s16x8*)(Vl + vr * 512 +
                            ((sub * 128 + ks * 32 + hi * 16) ^ ((vr & 7) << 4)));
        }

      // S'^T = K * Q'^T (K rows sub*64 + blk*32 + ql)
      f32x16 st[2][2] = {};             // [chunk][blk]
#pragma unroll
      for (int blk = 0; blk < 2; ++blk)
#pragma unroll
        for (int kq = 0; kq < 4; ++kq) {
          const int kr = sub * 64 + blk * 32 + ql;
          const s16x8 k8 = *(const s16x8*)(Kl + kr * 128 +
                             ((kq * 32 + hi * 16) ^ ((kr & 7) << 4)));
#pragma unroll
          for (int c = 0; c < 2; ++c)
            st[c][blk] = __builtin_amdgcn_mfma_f32_32x32x16_bf16(k8, qf[c][kq], st[c][blk], 0, 0, 0);
        }

      // streaming softmax: P = exp2(S'), accumulate per-half l. No shuffles.
#pragma unroll
      for (int c = 0; c < 2; ++c) {
#pragma unroll
        for (int blk = 0; blk < 2; ++blk)
#pragma unroll
          for (int r = 0; r < 16; ++r)
            st[c][blk][r] = __builtin_amdgcn_exp2f(st[c][blk][r]);
        l[c] += vsum16(st[c][0]) + vsum16(st[c][1]);
      }

      // PV per chunk: P^T fragments via cvt_pk + permlane32_swap, then 8 MFMA
#pragma unroll
      for (int c = 0; c < 2; ++c) {
        s16x8 pf[4];
#pragma unroll
        for (int ks = 0; ks < 4; ++ks) {
          const int blk = ks >> 1, rb = (ks & 1) * 8;
          unsigned int a0, a1, b0, b1;
          asm("v_cvt_pk_bf16_f32 %0, %1, %2" : "=v"(a0) : "v"(st[c][blk][rb + 0]), "v"(st[c][blk][rb + 1]));
          asm("v_cvt_pk_bf16_f32 %0, %1, %2" : "=v"(a1) : "v"(st[c][blk][rb + 2]), "v"(st[c][blk][rb + 3]));
          asm("v_cvt_pk_bf16_f32 %0, %1, %2" : "=v"(b0) : "v"(st[c][blk][rb + 4]), "v"(st[c][blk][rb + 5]));
          asm("v_cvt_pk_bf16_f32 %0, %1, %2" : "=v"(b1) : "v"(st[c][blk][rb + 6]), "v"(st[c][blk][rb + 7]));
          asm("v_permlane32_swap_b32 %0, %1" : "+v"(a0), "+v"(b0));
          asm("v_permlane32_swap_b32 %0, %1" : "+v"(a1), "+v"(b1));
          u32x4 w = {a0, a1, b0, b1};
          pf[ks] = __builtin_bit_cast(s16x8, w);
        }
#pragma unroll
        for (int ks = 0; ks < 4; ++ks)
#pragma unroll
          for (int dblk = 0; dblk < 2; ++dblk)
            ot[c][dblk] = __builtin_amdgcn_mfma_f32_32x32x16_bf16(vfr[ks][dblk], pf[ks], ot[c][dblk], 0, 0, 0);
      }
    }
  }

  // epilogue: merge per-half l across the 32-boundary, normalize, store bf16
#pragma unroll
  for (int c = 0; c < 2; ++c) {
    const float lt = l[c] + __shfl_xor(l[c], 32, 64);
    const float inv = 1.f / lt;
    const int orow = qkbase + (q0 + c * 32 + ql) * D_SZ;
#pragma unroll
    for (int dblk = 0; dblk < 2; ++dblk)
#pragma unroll
      for (int qd = 0; qd < 4; ++qd) {  // d = dblk*32 + qd*8 + hi*4 + (0..3)
        ushort4 pk;
        pk.x = f2b(ot[c][dblk][qd * 4 + 0] * inv);
        pk.y = f2b(ot[c][dblk][qd * 4 + 1] * inv);
        pk.z = f2b(ot[c][dblk][qd * 4 + 2] * inv);
        pk.w = f2b(ot[c][dblk][qd * 4 + 3] * inv);
        *(ushort4*)&O[orow + dblk * 32 + qd * 8 + hi * 4] = pk;
      }
  }
}

// ---------- launch ----------
extern "C" void kernel_launch(void* const* d_in, const int* in_sizes, int n_in,
                              void* d_out, int out_size, void* d_ws, size_t ws_size,
                              hipStream_t stream) {
  const float* x  = (const float*)d_in[0];
  const float* Wq = (const float*)d_in[1];
  const float* Wk = (const float*)d_in[2];
  const float* Wv = (const float*)d_in[3];
  const float* Wo = (const float*)d_in[4];

  const int NTOK = B_SZ * T_SZ;
  const int SZX = NTOK * D_SZ;
  const int SZW = D_SZ * D_SZ;

  unsigned short* ws  = (unsigned short*)d_ws;
  unsigned short* xb  = ws;             // x bf16; reused as attention output O
  unsigned short* wqb = xb + SZX;
  unsigned short* wkb = wqb + SZW;
  unsigned short* wvb = wkb + SZW;
  unsigned short* wob = wvb + SZW;
  unsigned short* Qb  = wob + SZW;
  unsigned short* Kb  = Qb + SZX;
  unsigned short* Vtb = Kb + SZX;       // V transposed per (b,h): [b*1024+c][t]

  cast_all<<<(2097152 + 4 * 262144) / 256, 256, 0, stream>>>(
      x, Wq, Wk, Wv, Wo, xb, wqb, wkb, wvb, wob);

  dim3 gq(NTOK / BM, 24);               // fused Q,K,V projections
  gemm_qkv<<<gq, 256, 0, stream>>>(xb, wqb, wkb, wvb, Qb, Kb, Vtb);

  dim3 ga(T_SZ / 256, B_SZ * NH);
  attn_kernel<<<ga, 256, 0, stream>>>(Qb, Kb, Vtb, xb);  // O overwrites xb

  dim3 gg(NTOK / BM, D_SZ / BN);
  gemm_out<<<gg, 256, 0, stream>>>(xb, wob, (float*)d_out, NTOK, D_SZ, D_SZ);
}

// Round 19
// 166.676 us; speedup vs baseline: 1.0003x; 1.0003x over previous
//
#include <hip/hip_runtime.h>

typedef float f32x4 __attribute__((ext_vector_type(4)));
typedef float f32x16 __attribute__((ext_vector_type(16)));
typedef short s16x8 __attribute__((ext_vector_type(8)));
typedef unsigned int u32x4 __attribute__((ext_vector_type(4)));

#define B_SZ 4
#define T_SZ 2048
#define D_SZ 1024
#define NH 16
#define HD 64
#define KVB 256

// scale folded into Q: hd^-0.5 * log2(e)
#define CLQ (0.125f * 1.44269504089f)

// ---------- helpers ----------
__device__ __forceinline__ unsigned short f2b(float f) {
  unsigned int u = __builtin_bit_cast(unsigned int, f);
  unsigned int r = (u + 0x7fffu + ((u >> 16) & 1u)) >> 16;  // RNE
  return (unsigned short)r;
}

__device__ __forceinline__ void gld_lds16(void* lds, const void* g) {
  __builtin_amdgcn_global_load_lds(
      (const __attribute__((address_space(1))) unsigned int*)g,
      (__attribute__((address_space(3))) unsigned int*)lds, 16, 0, 0);
}

__device__ __forceinline__ float vsum16(f32x16 v) {
  float t0 = (v[0] + v[1]) + (v[2] + v[3]);
  float t1 = (v[4] + v[5]) + (v[6] + v[7]);
  float t2 = (v[8] + v[9]) + (v[10] + v[11]);
  float t3 = (v[12] + v[13]) + (v[14] + v[15]);
  return (t0 + t1) + (t2 + t3);
}

// ---------- fp32 -> bf16 cast: x + all 4 weights in ONE dispatch ----------
__global__ void cast_all(const float* __restrict__ x,
                         const float* __restrict__ w0, const float* __restrict__ w1,
                         const float* __restrict__ w2, const float* __restrict__ w3,
                         unsigned short* __restrict__ xo,
                         unsigned short* __restrict__ o0, unsigned short* __restrict__ o1,
                         unsigned short* __restrict__ o2, unsigned short* __restrict__ o3) {
  int i = blockIdx.x * blockDim.x + threadIdx.x;
  const float* src;
  unsigned short* dst;
  int j;
  if (i < 2097152) {                 // x
    src = x; dst = xo; j = i;
  } else {
    const int t = i - 2097152;
    const int w = t >> 18;           // 262144 float4 per weight matrix
    j = t & 262143;
    src = (w == 0) ? w0 : (w == 1) ? w1 : (w == 2) ? w2 : w3;
    dst = (w == 0) ? o0 : (w == 1) ? o1 : (w == 2) ? o2 : o3;
  }
  float4 v = reinterpret_cast<const float4*>(src)[j];
  ushort4 o;
  o.x = f2b(v.x); o.y = f2b(v.y); o.z = f2b(v.z); o.w = f2b(v.w);
  reinterpret_cast<ushort4*>(dst)[j] = o;
}

// ---------- GEMM core (128x128 tile, BK=64, both-sides swizzle, R17-exact) ---
#define BM 128
#define BN 128
#define BKG 64

// Fused QKV projection: one dispatch, grid (64, 24). (R13/R17-verified)
__global__ __launch_bounds__(256, 2) void gemm_qkv(
    const unsigned short* __restrict__ A,
    const unsigned short* __restrict__ Wq,
    const unsigned short* __restrict__ Wk,
    const unsigned short* __restrict__ Wv,
    unsigned short* __restrict__ Qo,
    unsigned short* __restrict__ Ko,
    unsigned short* __restrict__ Vto) {
  __shared__ __align__(16) char As[BM * 128];
  __shared__ __align__(16) char Ws[BN * 128];
  const int tid = threadIdx.x, wid = tid >> 6, lane = tid & 63;
  const int sel = blockIdx.y >> 3;              // 0=Q 1=K 2=V
  const unsigned short* W = (sel == 0) ? Wq : (sel == 1) ? Wk : Wv;
  const int row0 = blockIdx.x * BM, col0 = (blockIdx.y & 7) * BN;
  const int wr = (wid >> 1) * 64, wc = (wid & 1) * 64;
  const int fr = lane & 15;
  const int kgB = (lane >> 4) * 16;
  f32x4 acc[4][4] = {};

  const int srow = lane >> 3;
  const int sc = lane & 7;
  const int sch = sc ^ srow;

  for (int k0 = 0; k0 < D_SZ; k0 += BKG) {
    __syncthreads();
#pragma unroll
    for (int i = 0; i < 4; ++i) {
      const int c = wid + 4 * i;
      const int row = c * 8 + srow;
      gld_lds16(As + c * 1024, &A[(row0 + row) * D_SZ + k0 + sch * 8]);
      gld_lds16(Ws + c * 1024, &W[(col0 + row) * D_SZ + k0 + sch * 8]);
    }
    __syncthreads();
    s16x8 af[4][2], bf[4][2];
#pragma unroll
    for (int m = 0; m < 4; ++m) {
      const int row = wr + m * 16 + fr;
#pragma unroll
      for (int kk = 0; kk < 2; ++kk)
        af[m][kk] = *(const s16x8*)(As + row * 128 + ((kk * 64 + kgB) ^ ((row & 7) << 4)));
    }
#pragma unroll
    for (int n = 0; n < 4; ++n) {
      const int row = wc + n * 16 + fr;
#pragma unroll
      for (int kk = 0; kk < 2; ++kk)
        bf[n][kk] = *(const s16x8*)(Ws + row * 128 + ((kk * 64 + kgB) ^ ((row & 7) << 4)));
    }
#pragma unroll
    for (int kk = 0; kk < 2; ++kk)
#pragma unroll
      for (int m = 0; m < 4; ++m)
#pragma unroll
        for (int n = 0; n < 4; ++n)
          acc[m][n] = __builtin_amdgcn_mfma_f32_16x16x32_bf16(af[m][kk], bf[n][kk], acc[m][n], 0, 0, 0);
  }

  const int crow = row0 + wr + ((lane >> 4) << 2);
  const int ccol = col0 + wc + fr;
  if (sel == 2) {  // Vt: transposed per (b,h)
#pragma unroll
    for (int m = 0; m < 4; ++m)
#pragma unroll
      for (int n = 0; n < 4; ++n) {
        ushort4 pk;
        pk.x = f2b(acc[m][n][0]); pk.y = f2b(acc[m][n][1]);
        pk.z = f2b(acc[m][n][2]); pk.w = f2b(acc[m][n][3]);
        const int tok = crow + m * 16;
        const int c = ccol + n * 16;
        *(ushort4*)&Vto[((tok >> 11) * 1024 + c) * 2048 + (tok & 2047)] = pk;
      }
  } else {
    unsigned short* C = (sel == 0) ? Qo : Ko;
    const float s = (sel == 0) ? CLQ : 1.0f;
#pragma unroll
    for (int m = 0; m < 4; ++m)
#pragma unroll
      for (int n = 0; n < 4; ++n)
#pragma unroll
        for (int r = 0; r < 4; ++r)
          C[(crow + m * 16 + r) * D_SZ + ccol + n * 16] = f2b(acc[m][n][r] * s);
  }
}

// O-projection: C[M,N] f32 = A[M,K] * W[N,K]^T  (R17-exact)
__global__ __launch_bounds__(256, 2) void gemm_out(
    const unsigned short* __restrict__ A,
    const unsigned short* __restrict__ W,
    float* __restrict__ C, int M, int N, int K) {
  __shared__ __align__(16) char As[BM * 128];
  __shared__ __align__(16) char Ws[BN * 128];
  const int tid = threadIdx.x, wid = tid >> 6, lane = tid & 63;
  const int row0 = blockIdx.x * BM, col0 = blockIdx.y * BN;
  const int wr = (wid >> 1) * 64, wc = (wid & 1) * 64;
  const int fr = lane & 15;
  const int kgB = (lane >> 4) * 16;
  f32x4 acc[4][4] = {};

  const int srow = lane >> 3;
  const int sc = lane & 7;
  const int sch = sc ^ srow;

  for (int k0 = 0; k0 < K; k0 += BKG) {
    __syncthreads();
#pragma unroll
    for (int i = 0; i < 4; ++i) {
      const int c = wid + 4 * i;
      const int row = c * 8 + srow;
      gld_lds16(As + c * 1024, &A[(row0 + row) * K + k0 + sch * 8]);
      gld_lds16(Ws + c * 1024, &W[(col0 + row) * K + k0 + sch * 8]);
    }
    __syncthreads();
    s16x8 af[4][2], bf[4][2];
#pragma unroll
    for (int m = 0; m < 4; ++m) {
      const int row = wr + m * 16 + fr;
#pragma unroll
      for (int kk = 0; kk < 2; ++kk)
        af[m][kk] = *(const s16x8*)(As + row * 128 + ((kk * 64 + kgB) ^ ((row & 7) << 4)));
    }
#pragma unroll
    for (int n = 0; n < 4; ++n) {
      const int row = wc + n * 16 + fr;
#pragma unroll
      for (int kk = 0; kk < 2; ++kk)
        bf[n][kk] = *(const s16x8*)(Ws + row * 128 + ((kk * 64 + kgB) ^ ((row & 7) << 4)));
    }
#pragma unroll
    for (int kk = 0; kk < 2; ++kk)
#pragma unroll
      for (int m = 0; m < 4; ++m)
#pragma unroll
        for (int n = 0; n < 4; ++n)
          acc[m][n] = __builtin_amdgcn_mfma_f32_16x16x32_bf16(af[m][kk], bf[n][kk], acc[m][n], 0, 0, 0);
  }

  const int crow = row0 + wr + ((lane >> 4) << 2);
  const int ccol = col0 + wc + fr;
#pragma unroll
  for (int m = 0; m < 4; ++m)
#pragma unroll
    for (int n = 0; n < 4; ++n)
#pragma unroll
      for (int r = 0; r < 4; ++r)
        C[(crow + m * 16 + r) * N + ccol + n * 16] = acc[m][n][r];
}

// ---------- flash attention: KVB=256 (R17-verified) + T5 setprio -------------
// block = 4 waves x 64 q = 256 q; grid (8, 64) = 512 blocks, XCD-swizzled.
// Within a 256-kv round the 4 sub-iterations have no barriers -> waves drift
// into different phases (QK/softmax/PV) — T5's role-diversity prerequisite.
// setprio(1) around the MFMA clusters keeps the matrix pipe fed (m191 case).
__global__ __launch_bounds__(256, 2) void attn_kernel(
    const unsigned short* __restrict__ Q,
    const unsigned short* __restrict__ K,
    const unsigned short* __restrict__ Vt,
    unsigned short* __restrict__ O) {
  __shared__ __align__(16) char Kl[KVB * 128];   // [kv 0..255][128B], swizzled
  __shared__ __align__(16) char Vl[HD * 512];    // [d 0..63][512B], swizzled per 128B group

  const int tid = threadIdx.x, wid = tid >> 6, lane = tid & 63;
  const int ql = lane & 31;
  const int hi = lane >> 5;
  const int srow = lane >> 3;    // K staging: row within 8-row chunk
  const int sc = lane & 7;       // K staging: 16B chunk within 128B row
  const int vrow = lane >> 5;    // V staging: row within 2-row chunk (512B rows)
  const int vsc = lane & 31;     // V staging: 16B slot within 512B row

  // bijective XCD swizzle: 512 blocks = 8 XCD * 64
  const int lin = blockIdx.y * gridDim.x + blockIdx.x;
  const int work = (lin & 7) * 64 + (lin >> 3);
  const int qc = work & 7, bh = work >> 3;
  const int b = bh >> 4, h = bh & 15;
  const int q0 = qc * 256 + wid * 64;
  const int qkbase = b * T_SZ * D_SZ + h * HD;
  const int vtbase = (b * D_SZ + h * HD) * T_SZ;

  // Q B-fragments for both chunks (already scaled by CLQ)
  s16x8 qf[2][4];
#pragma unroll
  for (int c = 0; c < 2; ++c)
#pragma unroll
    for (int kq = 0; kq < 4; ++kq)
      qf[c][kq] = *(const s16x8*)&Q[qkbase + (q0 + c * 32 + ql) * D_SZ + kq * 16 + hi * 8];

  f32x16 ot[2][2] = {};             // [chunk][dblk]
  float l[2] = {0.f, 0.f};          // per-half partial sums

#pragma unroll 1
  for (int kv0 = 0; kv0 < T_SZ; kv0 += KVB) {
    __syncthreads();  // previous round's LDS reads complete
#pragma unroll
    for (int i = 0; i < 8; ++i) {
      const int c = wid + 4 * i;
      const int row = c * 8 + srow;
      const int sch = sc ^ (row & 7);
      gld_lds16(Kl + c * 1024, &K[qkbase + (kv0 + row) * D_SZ + sch * 8]);
    }
#pragma unroll
    for (int i = 0; i < 8; ++i) {
      const int c = wid + 4 * i;
      const int row = c * 2 + vrow;
      const int sslot = vsc ^ (row & 7);
      gld_lds16(Vl + c * 1024, &Vt[vtbase + row * T_SZ + kv0 + sslot * 8]);
    }
    __syncthreads();  // staging visible (syncthreads drains vmcnt)

#pragma unroll 1
    for (int sub = 0; sub < 4; ++sub) {
      // V fragments (8 ds_read_b128), slots in sub's 128B group
      s16x8 vfr[4][2];
#pragma unroll
      for (int ks = 0; ks < 4; ++ks)
#pragma unroll
        for (int dblk = 0; dblk < 2; ++dblk) {
          const int vr = dblk * 32 + ql;
          vfr[ks][dblk] = *(const s16x8*)(Vl + vr * 512 +
                            ((sub * 128 + ks * 32 + hi * 16) ^ ((vr & 7) << 4)));
        }

      // S'^T = K * Q'^T (K rows sub*64 + blk*32 + ql)
      f32x16 st[2][2] = {};             // [chunk][blk]
      __builtin_amdgcn_s_setprio(1);
#pragma unroll
      for (int blk = 0; blk < 2; ++blk)
#pragma unroll
        for (int kq = 0; kq < 4; ++kq) {
          const int kr = sub * 64 + blk * 32 + ql;
          const s16x8 k8 = *(const s16x8*)(Kl + kr * 128 +
                             ((kq * 32 + hi * 16) ^ ((kr & 7) << 4)));
#pragma unroll
          for (int c = 0; c < 2; ++c)
            st[c][blk] = __builtin_amdgcn_mfma_f32_32x32x16_bf16(k8, qf[c][kq], st[c][blk], 0, 0, 0);
        }
      __builtin_amdgcn_s_setprio(0);

      // streaming softmax: P = exp2(S'), accumulate per-half l. No shuffles.
#pragma unroll
      for (int c = 0; c < 2; ++c) {
#pragma unroll
        for (int blk = 0; blk < 2; ++blk)
#pragma unroll
          for (int r = 0; r < 16; ++r)
            st[c][blk][r] = __builtin_amdgcn_exp2f(st[c][blk][r]);
        l[c] += vsum16(st[c][0]) + vsum16(st[c][1]);
      }

      // PV per chunk: P^T fragments via cvt_pk + permlane32_swap, then 8 MFMA
#pragma unroll
      for (int c = 0; c < 2; ++c) {
        s16x8 pf[4];
#pragma unroll
        for (int ks = 0; ks < 4; ++ks) {
          const int blk = ks >> 1, rb = (ks & 1) * 8;
          unsigned int a0, a1, b0, b1;
          asm("v_cvt_pk_bf16_f32 %0, %1, %2" : "=v"(a0) : "v"(st[c][blk][rb + 0]), "v"(st[c][blk][rb + 1]));
          asm("v_cvt_pk_bf16_f32 %0, %1, %2" : "=v"(a1) : "v"(st[c][blk][rb + 2]), "v"(st[c][blk][rb + 3]));
          asm("v_cvt_pk_bf16_f32 %0, %1, %2" : "=v"(b0) : "v"(st[c][blk][rb + 4]), "v"(st[c][blk][rb + 5]));
          asm("v_cvt_pk_bf16_f32 %0, %1, %2" : "=v"(b1) : "v"(st[c][blk][rb + 6]), "v"(st[c][blk][rb + 7]));
          asm("v_permlane32_swap_b32 %0, %1" : "+v"(a0), "+v"(b0));
          asm("v_permlane32_swap_b32 %0, %1" : "+v"(a1), "+v"(b1));
          u32x4 w = {a0, a1, b0, b1};
          pf[ks] = __builtin_bit_cast(s16x8, w);
        }
        __builtin_amdgcn_s_setprio(1);
#pragma unroll
        for (int ks = 0; ks < 4; ++ks)
#pragma unroll
          for (int dblk = 0; dblk < 2; ++dblk)
            ot[c][dblk] = __builtin_amdgcn_mfma_f32_32x32x16_bf16(vfr[ks][dblk], pf[ks], ot[c][dblk], 0, 0, 0);
        __builtin_amdgcn_s_setprio(0);
      }
    }
  }

  // epilogue: merge per-half l across the 32-boundary, normalize, store bf16
#pragma unroll
  for (int c = 0; c < 2; ++c) {
    const float lt = l[c] + __shfl_xor(l[c], 32, 64);
    const float inv = 1.f / lt;
    const int orow = qkbase + (q0 + c * 32 + ql) * D_SZ;
#pragma unroll
    for (int dblk = 0; dblk < 2; ++dblk)
#pragma unroll
      for (int qd = 0; qd < 4; ++qd) {  // d = dblk*32 + qd*8 + hi*4 + (0..3)
        ushort4 pk;
        pk.x = f2b(ot[c][dblk][qd * 4 + 0] * inv);
        pk.y = f2b(ot[c][dblk][qd * 4 + 1] * inv);
        pk.z = f2b(ot[c][dblk][qd * 4 + 2] * inv);
        pk.w = f2b(ot[c][dblk][qd * 4 + 3] * inv);
        *(ushort4*)&O[orow + dblk * 32 + qd * 8 + hi * 4] = pk;
      }
  }
}

// ---------- launch ----------
extern "C" void kernel_launch(void* const* d_in, const int* in_sizes, int n_in,
                              void* d_out, int out_size, void* d_ws, size_t ws_size,
                              hipStream_t stream) {
  const float* x  = (const float*)d_in[0];
  const float* Wq = (const float*)d_in[1];
  const float* Wk = (const float*)d_in[2];
  const float* Wv = (const float*)d_in[3];
  const float* Wo = (const float*)d_in[4];

  const int NTOK = B_SZ * T_SZ;
  const int SZX = NTOK * D_SZ;
  const int SZW = D_SZ * D_SZ;

  unsigned short* ws  = (unsigned short*)d_ws;
  unsigned short* xb  = ws;             // x bf16; reused as attention output O
  unsigned short* wqb = xb + SZX;
  unsigned short* wkb = wqb + SZW;
  unsigned short* wvb = wkb + SZW;
  unsigned short* wob = wvb + SZW;
  unsigned short* Qb  = wob + SZW;
  unsigned short* Kb  = Qb + SZX;
  unsigned short* Vtb = Kb + SZX;       // V transposed per (b,h): [b*1024+c][t]

  cast_all<<<(2097152 + 4 * 262144) / 256, 256, 0, stream>>>(
      x, Wq, Wk, Wv, Wo, xb, wqb, wkb, wvb, wob);

  dim3 gq(NTOK / BM, 24);               // fused Q,K,V projections
  gemm_qkv<<<gq, 256, 0, stream>>>(xb, wqb, wkb, wvb, Qb, Kb, Vtb);

  dim3 ga(T_SZ / 256, B_SZ * NH);
  attn_kernel<<<ga, 256, 0, stream>>>(Qb, Kb, Vtb, xb);  // O overwrites xb

  dim3 gg(NTOK / BM, D_SZ / BN);
  gemm_out<<<gg, 256, 0, stream>>>(xb, wob, (float*)d_out, NTOK, D_SZ, D_SZ);
}

// Round 20
// 161.603 us; speedup vs baseline: 1.0317x; 1.0314x over previous
//
#include <hip/hip_runtime.h>

typedef float f32x4 __attribute__((ext_vector_type(4)));
typedef float f32x16 __attribute__((ext_vector_type(16)));
typedef short s16x8 __attribute__((ext_vector_type(8)));
typedef unsigned int u32x4 __attribute__((ext_vector_type(4)));

#define B_SZ 4
#define T_SZ 2048
#define D_SZ 1024
#define NH 16
#define HD 64
#define KVB 256

// scale folded into Q: hd^-0.5 * log2(e)
#define CLQ (0.125f * 1.44269504089f)

// ---------- helpers ----------
__device__ __forceinline__ unsigned short f2b(float f) {
  unsigned int u = __builtin_bit_cast(unsigned int, f);
  unsigned int r = (u + 0x7fffu + ((u >> 16) & 1u)) >> 16;  // RNE
  return (unsigned short)r;
}

__device__ __forceinline__ void gld_lds16(void* lds, const void* g) {
  __builtin_amdgcn_global_load_lds(
      (const __attribute__((address_space(1))) unsigned int*)g,
      (__attribute__((address_space(3))) unsigned int*)lds, 16, 0, 0);
}

__device__ __forceinline__ float vsum16(f32x16 v) {
  float t0 = (v[0] + v[1]) + (v[2] + v[3]);
  float t1 = (v[4] + v[5]) + (v[6] + v[7]);
  float t2 = (v[8] + v[9]) + (v[10] + v[11]);
  float t3 = (v[12] + v[13]) + (v[14] + v[15]);
  return (t0 + t1) + (t2 + t3);
}

// ---------- fp32 -> bf16 cast: x + all 4 weights in ONE dispatch ----------
__global__ void cast_all(const float* __restrict__ x,
                         const float* __restrict__ w0, const float* __restrict__ w1,
                         const float* __restrict__ w2, const float* __restrict__ w3,
                         unsigned short* __restrict__ xo,
                         unsigned short* __restrict__ o0, unsigned short* __restrict__ o1,
                         unsigned short* __restrict__ o2, unsigned short* __restrict__ o3) {
  int i = blockIdx.x * blockDim.x + threadIdx.x;
  const float* src;
  unsigned short* dst;
  int j;
  if (i < 2097152) {                 // x
    src = x; dst = xo; j = i;
  } else {
    const int t = i - 2097152;
    const int w = t >> 18;           // 262144 float4 per weight matrix
    j = t & 262143;
    src = (w == 0) ? w0 : (w == 1) ? w1 : (w == 2) ? w2 : w3;
    dst = (w == 0) ? o0 : (w == 1) ? o1 : (w == 2) ? o2 : o3;
  }
  float4 v = reinterpret_cast<const float4*>(src)[j];
  ushort4 o;
  o.x = f2b(v.x); o.y = f2b(v.y); o.z = f2b(v.z); o.w = f2b(v.w);
  reinterpret_cast<ushort4*>(dst)[j] = o;
}

// ---------- GEMM core (128x128 tile, BK=64, both-sides swizzle, R17-exact) ---
#define BM 128
#define BN 128
#define BKG 64

// Fused QKV projection: one dispatch, grid (64, 24). (R13/R17-verified)
__global__ __launch_bounds__(256, 2) void gemm_qkv(
    const unsigned short* __restrict__ A,
    const unsigned short* __restrict__ Wq,
    const unsigned short* __restrict__ Wk,
    const unsigned short* __restrict__ Wv,
    unsigned short* __restrict__ Qo,
    unsigned short* __restrict__ Ko,
    unsigned short* __restrict__ Vto) {
  __shared__ __align__(16) char As[BM * 128];
  __shared__ __align__(16) char Ws[BN * 128];
  const int tid = threadIdx.x, wid = tid >> 6, lane = tid & 63;
  const int sel = blockIdx.y >> 3;              // 0=Q 1=K 2=V
  const unsigned short* W = (sel == 0) ? Wq : (sel == 1) ? Wk : Wv;
  const int row0 = blockIdx.x * BM, col0 = (blockIdx.y & 7) * BN;
  const int wr = (wid >> 1) * 64, wc = (wid & 1) * 64;
  const int fr = lane & 15;
  const int kgB = (lane >> 4) * 16;
  f32x4 acc[4][4] = {};

  const int srow = lane >> 3;
  const int sc = lane & 7;
  const int sch = sc ^ srow;

  for (int k0 = 0; k0 < D_SZ; k0 += BKG) {
    __syncthreads();
#pragma unroll
    for (int i = 0; i < 4; ++i) {
      const int c = wid + 4 * i;
      const int row = c * 8 + srow;
      gld_lds16(As + c * 1024, &A[(row0 + row) * D_SZ + k0 + sch * 8]);
      gld_lds16(Ws + c * 1024, &W[(col0 + row) * D_SZ + k0 + sch * 8]);
    }
    __syncthreads();
    s16x8 af[4][2], bf[4][2];
#pragma unroll
    for (int m = 0; m < 4; ++m) {
      const int row = wr + m * 16 + fr;
#pragma unroll
      for (int kk = 0; kk < 2; ++kk)
        af[m][kk] = *(const s16x8*)(As + row * 128 + ((kk * 64 + kgB) ^ ((row & 7) << 4)));
    }
#pragma unroll
    for (int n = 0; n < 4; ++n) {
      const int row = wc + n * 16 + fr;
#pragma unroll
      for (int kk = 0; kk < 2; ++kk)
        bf[n][kk] = *(const s16x8*)(Ws + row * 128 + ((kk * 64 + kgB) ^ ((row & 7) << 4)));
    }
#pragma unroll
    for (int kk = 0; kk < 2; ++kk)
#pragma unroll
      for (int m = 0; m < 4; ++m)
#pragma unroll
        for (int n = 0; n < 4; ++n)
          acc[m][n] = __builtin_amdgcn_mfma_f32_16x16x32_bf16(af[m][kk], bf[n][kk], acc[m][n], 0, 0, 0);
  }

  const int crow = row0 + wr + ((lane >> 4) << 2);
  const int ccol = col0 + wc + fr;
  if (sel == 2) {  // Vt: transposed per (b,h)
#pragma unroll
    for (int m = 0; m < 4; ++m)
#pragma unroll
      for (int n = 0; n < 4; ++n) {
        ushort4 pk;
        pk.x = f2b(acc[m][n][0]); pk.y = f2b(acc[m][n][1]);
        pk.z = f2b(acc[m][n][2]); pk.w = f2b(acc[m][n][3]);
        const int tok = crow + m * 16;
        const int c = ccol + n * 16;
        *(ushort4*)&Vto[((tok >> 11) * 1024 + c) * 2048 + (tok & 2047)] = pk;
      }
  } else {
    unsigned short* C = (sel == 0) ? Qo : Ko;
    const float s = (sel == 0) ? CLQ : 1.0f;
#pragma unroll
    for (int m = 0; m < 4; ++m)
#pragma unroll
      for (int n = 0; n < 4; ++n)
#pragma unroll
        for (int r = 0; r < 4; ++r)
          C[(crow + m * 16 + r) * D_SZ + ccol + n * 16] = f2b(acc[m][n][r] * s);
  }
}

// O-projection: C[M,N] f32 = A[M,K] * W[N,K]^T  (R17-exact)
__global__ __launch_bounds__(256, 2) void gemm_out(
    const unsigned short* __restrict__ A,
    const unsigned short* __restrict__ W,
    float* __restrict__ C, int M, int N, int K) {
  __shared__ __align__(16) char As[BM * 128];
  __shared__ __align__(16) char Ws[BN * 128];
  const int tid = threadIdx.x, wid = tid >> 6, lane = tid & 63;
  const int row0 = blockIdx.x * BM, col0 = blockIdx.y * BN;
  const int wr = (wid >> 1) * 64, wc = (wid & 1) * 64;
  const int fr = lane & 15;
  const int kgB = (lane >> 4) * 16;
  f32x4 acc[4][4] = {};

  const int srow = lane >> 3;
  const int sc = lane & 7;
  const int sch = sc ^ srow;

  for (int k0 = 0; k0 < K; k0 += BKG) {
    __syncthreads();
#pragma unroll
    for (int i = 0; i < 4; ++i) {
      const int c = wid + 4 * i;
      const int row = c * 8 + srow;
      gld_lds16(As + c * 1024, &A[(row0 + row) * K + k0 + sch * 8]);
      gld_lds16(Ws + c * 1024, &W[(col0 + row) * K + k0 + sch * 8]);
    }
    __syncthreads();
    s16x8 af[4][2], bf[4][2];
#pragma unroll
    for (int m = 0; m < 4; ++m) {
      const int row = wr + m * 16 + fr;
#pragma unroll
      for (int kk = 0; kk < 2; ++kk)
        af[m][kk] = *(const s16x8*)(As + row * 128 + ((kk * 64 + kgB) ^ ((row & 7) << 4)));
    }
#pragma unroll
    for (int n = 0; n < 4; ++n) {
      const int row = wc + n * 16 + fr;
#pragma unroll
      for (int kk = 0; kk < 2; ++kk)
        bf[n][kk] = *(const s16x8*)(Ws + row * 128 + ((kk * 64 + kgB) ^ ((row & 7) << 4)));
    }
#pragma unroll
    for (int kk = 0; kk < 2; ++kk)
#pragma unroll
      for (int m = 0; m < 4; ++m)
#pragma unroll
        for (int n = 0; n < 4; ++n)
          acc[m][n] = __builtin_amdgcn_mfma_f32_16x16x32_bf16(af[m][kk], bf[n][kk], acc[m][n], 0, 0, 0);
  }

  const int crow = row0 + wr + ((lane >> 4) << 2);
  const int ccol = col0 + wc + fr;
#pragma unroll
  for (int m = 0; m < 4; ++m)
#pragma unroll
    for (int n = 0; n < 4; ++n)
#pragma unroll
      for (int r = 0; r < 4; ++r)
        C[(crow + m * 16 + r) * N + ccol + n * 16] = acc[m][n][r];
}

// ---------- flash attention: KVB=256, single-body sub loop (R17-exact) -------
// block = 4 waves x 64 q = 256 q; grid (8, 64) = 512 blocks, XCD-swizzled.
__global__ __launch_bounds__(256, 2) void attn_kernel(
    const unsigned short* __restrict__ Q,
    const unsigned short* __restrict__ K,
    const unsigned short* __restrict__ Vt,
    unsigned short* __restrict__ O) {
  __shared__ __align__(16) char Kl[KVB * 128];   // [kv 0..255][128B], swizzled
  __shared__ __align__(16) char Vl[HD * 512];    // [d 0..63][512B], swizzled per 128B group

  const int tid = threadIdx.x, wid = tid >> 6, lane = tid & 63;
  const int ql = lane & 31;
  const int hi = lane >> 5;
  const int srow = lane >> 3;    // K staging: row within 8-row chunk
  const int sc = lane & 7;       // K staging: 16B chunk within 128B row
  const int vrow = lane >> 5;    // V staging: row within 2-row chunk (512B rows)
  const int vsc = lane & 31;     // V staging: 16B slot within 512B row

  // bijective XCD swizzle: 512 blocks = 8 XCD * 64
  const int lin = blockIdx.y * gridDim.x + blockIdx.x;
  const int work = (lin & 7) * 64 + (lin >> 3);
  const int qc = work & 7, bh = work >> 3;
  const int b = bh >> 4, h = bh & 15;
  const int q0 = qc * 256 + wid * 64;
  const int qkbase = b * T_SZ * D_SZ + h * HD;
  const int vtbase = (b * D_SZ + h * HD) * T_SZ;

  // Q B-fragments for both chunks (already scaled by CLQ)
  s16x8 qf[2][4];
#pragma unroll
  for (int c = 0; c < 2; ++c)
#pragma unroll
    for (int kq = 0; kq < 4; ++kq)
      qf[c][kq] = *(const s16x8*)&Q[qkbase + (q0 + c * 32 + ql) * D_SZ + kq * 16 + hi * 8];

  f32x16 ot[2][2] = {};             // [chunk][dblk]
  float l[2] = {0.f, 0.f};          // per-half partial sums

#pragma unroll 1
  for (int kv0 = 0; kv0 < T_SZ; kv0 += KVB) {
    __syncthreads();  // previous round's LDS reads complete
#pragma unroll
    for (int i = 0; i < 8; ++i) {
      const int c = wid + 4 * i;
      const int row = c * 8 + srow;
      const int sch = sc ^ (row & 7);
      gld_lds16(Kl + c * 1024, &K[qkbase + (kv0 + row) * D_SZ + sch * 8]);
    }
#pragma unroll
    for (int i = 0; i < 8; ++i) {
      const int c = wid + 4 * i;
      const int row = c * 2 + vrow;
      const int sslot = vsc ^ (row & 7);
      gld_lds16(Vl + c * 1024, &Vt[vtbase + row * T_SZ + kv0 + sslot * 8]);
    }
    __syncthreads();  // staging visible (syncthreads drains vmcnt)

#pragma unroll 1
    for (int sub = 0; sub < 4; ++sub) {
      // V fragments (8 ds_read_b128), slots in sub's 128B group
      s16x8 vfr[4][2];
#pragma unroll
      for (int ks = 0; ks < 4; ++ks)
#pragma unroll
        for (int dblk = 0; dblk < 2; ++dblk) {
          const int vr = dblk * 32 + ql;
          vfr[ks][dblk] = *(const s16x8*)(Vl + vr * 512 +
                            ((sub * 128 + ks * 32 + hi * 16) ^ ((vr & 7) << 4)));
        }

      // S'^T = K * Q'^T (K rows sub*64 + blk*32 + ql)
      f32x16 st[2][2] = {};             // [chunk][blk]
#pragma unroll
      for (int blk = 0; blk < 2; ++blk)
#pragma unroll
        for (int kq = 0; kq < 4; ++kq) {
          const int kr = sub * 64 + blk * 32 + ql;
          const s16x8 k8 = *(const s16x8*)(Kl + kr * 128 +
                             ((kq * 32 + hi * 16) ^ ((kr & 7) << 4)));
#pragma unroll
          for (int c = 0; c < 2; ++c)
            st[c][blk] = __builtin_amdgcn_mfma_f32_32x32x16_bf16(k8, qf[c][kq], st[c][blk], 0, 0, 0);
        }

      // streaming softmax: P = exp2(S'), accumulate per-half l. No shuffles.
#pragma unroll
      for (int c = 0; c < 2; ++c) {
#pragma unroll
        for (int blk = 0; blk < 2; ++blk)
#pragma unroll
          for (int r = 0; r < 16; ++r)
            st[c][blk][r] = __builtin_amdgcn_exp2f(st[c][blk][r]);
        l[c] += vsum16(st[c][0]) + vsum16(st[c][1]);
      }

      // PV per chunk: P^T fragments via cvt_pk + permlane32_swap, then 8 MFMA
#pragma unroll
      for (int c = 0; c < 2; ++c) {
        s16x8 pf[4];
#pragma unroll
        for (int ks = 0; ks < 4; ++ks) {
          const int blk = ks >> 1, rb = (ks & 1) * 8;
          unsigned int a0, a1, b0, b1;
          asm("v_cvt_pk_bf16_f32 %0, %1, %2" : "=v"(a0) : "v"(st[c][blk][rb + 0]), "v"(st[c][blk][rb + 1]));
          asm("v_cvt_pk_bf16_f32 %0, %1, %2" : "=v"(a1) : "v"(st[c][blk][rb + 2]), "v"(st[c][blk][rb + 3]));
          asm("v_cvt_pk_bf16_f32 %0, %1, %2" : "=v"(b0) : "v"(st[c][blk][rb + 4]), "v"(st[c][blk][rb + 5]));
          asm("v_cvt_pk_bf16_f32 %0, %1, %2" : "=v"(b1) : "v"(st[c][blk][rb + 6]), "v"(st[c][blk][rb + 7]));
          asm("v_permlane32_swap_b32 %0, %1" : "+v"(a0), "+v"(b0));
          asm("v_permlane32_swap_b32 %0, %1" : "+v"(a1), "+v"(b1));
          u32x4 w = {a0, a1, b0, b1};
          pf[ks] = __builtin_bit_cast(s16x8, w);
        }
#pragma unroll
        for (int ks = 0; ks < 4; ++ks)
#pragma unroll
          for (int dblk = 0; dblk < 2; ++dblk)
            ot[c][dblk] = __builtin_amdgcn_mfma_f32_32x32x16_bf16(vfr[ks][dblk], pf[ks], ot[c][dblk], 0, 0, 0);
      }
    }
  }

  // epilogue: merge per-half l across the 32-boundary, normalize, store bf16
#pragma unroll
  for (int c = 0; c < 2; ++c) {
    const float lt = l[c] + __shfl_xor(l[c], 32, 64);
    const float inv = 1.f / lt;
    const int orow = qkbase + (q0 + c * 32 + ql) * D_SZ;
#pragma unroll
    for (int dblk = 0; dblk < 2; ++dblk)
#pragma unroll
      for (int qd = 0; qd < 4; ++qd) {  // d = dblk*32 + qd*8 + hi*4 + (0..3)
        ushort4 pk;
        pk.x = f2b(ot[c][dblk][qd * 4 + 0] * inv);
        pk.y = f2b(ot[c][dblk][qd * 4 + 1] * inv);
        pk.z = f2b(ot[c][dblk][qd * 4 + 2] * inv);
        pk.w = f2b(ot[c][dblk][qd * 4 + 3] * inv);
        *(ushort4*)&O[orow + dblk * 32 + qd * 8 + hi * 4] = pk;
      }
  }
}

// ---------- launch ----------
extern "C" void kernel_launch(void* const* d_in, const int* in_sizes, int n_in,
                              void* d_out, int out_size, void* d_ws, size_t ws_size,
                              hipStream_t stream) {
  const float* x  = (const float*)d_in[0];
  const float* Wq = (const float*)d_in[1];
  const float* Wk = (const float*)d_in[2];
  const float* Wv = (const float*)d_in[3];
  const float* Wo = (const float*)d_in[4];

  const int NTOK = B_SZ * T_SZ;
  const int SZX = NTOK * D_SZ;
  const int SZW = D_SZ * D_SZ;

  unsigned short* ws  = (unsigned short*)d_ws;
  unsigned short* xb  = ws;             // x bf16; reused as attention output O
  unsigned short* wqb = xb + SZX;
  unsigned short* wkb = wqb + SZW;
  unsigned short* wvb = wkb + SZW;
  unsigned short* wob = wvb + SZW;
  unsigned short* Qb  = wob + SZW;
  unsigned short* Kb  = Qb + SZX;
  unsigned short* Vtb = Kb + SZX;       // V transposed per (b,h): [b*1024+c][t]

  cast_all<<<(2097152 + 4 * 262144) / 256, 256, 0, stream>>>(
      x, Wq, Wk, Wv, Wo, xb, wqb, wkb, wvb, wob);

  dim3 gq(NTOK / BM, 24);               // fused Q,K,V projections
  gemm_qkv<<<gq, 256, 0, stream>>>(xb, wqb, wkb, wvb, Qb, Kb, Vtb);

  dim3 ga(T_SZ / 256, B_SZ * NH);
  attn_kernel<<<ga, 256, 0, stream>>>(Qb, Kb, Vtb, xb);  // O overwrites xb

  dim3 gg(NTOK / BM, D_SZ / BN);
  gemm_out<<<gg, 256, 0, stream>>>(xb, wob, (float*)d_out, NTOK, D_SZ, D_SZ);
}